// Round 10
// baseline (176.640 us; speedup 1.0000x reference)
//
#include <hip/hip_runtime.h>
#include <stdint.h>

#define BATCH   32768
#define NBITS   512
#define NWORDS  512          // BATCH / 64
#define NSLICE  32           // K-split: 36 tiles * 32 = 1152 blocks
#define SW      16           // words per slice = NWORDS / NSLICE
#define NTILE   36           // 8x8 lower-triangle of 64x64 tiles
#define MIGRID  512

typedef unsigned long long u64;

// ---------------------------------------------------------------------------
// Pass 1: bit-pack + f64 log table + zero c1/done.  (unchanged, R5/R9 shape)
// ---------------------------------------------------------------------------
__global__ __launch_bounds__(256) void pack_kernel(const float* __restrict__ bits,
                                                   u64* __restrict__ packed,
                                                   double* __restrict__ lg,
                                                   int* __restrict__ c1,
                                                   int* __restrict__ done) {
    const int gid = blockIdx.x * 256 + threadIdx.x;   // 0..131071

    if (gid <= BATCH) lg[gid] = (gid > 0) ? log((double)gid) : 0.0;
    if (gid < NBITS) c1[gid] = 0;
    if (gid == NBITS) *done = 0;

    const int wv   = threadIdx.x >> 6;
    const int lane = threadIdx.x & 63;
    const int gw   = blockIdx.x * 4 + wv;     // 0..2047
    const int w    = gw >> 2;                 // word 0..511
    const int q    = gw & 3;                  // column quarter
    const int c0   = q * 128 + lane * 2;

    u64 m0 = 0, m1 = 0;
    const float* base = bits + (size_t)w * 64 * NBITS + c0;
#pragma unroll 16
    for (int r = 0; r < 64; ++r) {
        float2 v = *reinterpret_cast<const float2*>(base + (size_t)r * NBITS);
        const u64 b = 1ull << r;
        if (v.x > 0.0f) m0 |= b;
        if (v.y > 0.0f) m1 |= b;
    }
    ulonglong2 st; st.x = m0; st.y = m1;
    *reinterpret_cast<ulonglong2*>(&packed[(size_t)w * NBITS + c0]) = st;
}

// ---------------------------------------------------------------------------
// Pass 2: partial Gram (R9 shape) with DIAGNOSTIC nrep repeat. Each rep
// re-stages and re-computes identical results (idempotent stores); runtime
// nrep + memory-clobber asm prevent hoisting/DCE. c1 atomics on rep 0 only.
// t_gram = dispatch_dur / nrep.
// ---------------------------------------------------------------------------
__global__ __launch_bounds__(256) void gram_kernel(const u64* __restrict__ packed,
                                                   unsigned short* __restrict__ Cp,
                                                   int* __restrict__ c1,
                                                   int nrep) {
    __shared__ u64 ldsI[SW][64];
    __shared__ u64 ldsJ[SW][64];

    const int s = blockIdx.x & (NSLICE - 1);  // K-slice 0..31
    const int t = blockIdx.x >> 5;            // tile 0..35
    int bi = (int)((sqrtf(8.0f * (float)t + 1.0f) - 1.0f) * 0.5f);
    while ((bi + 1) * (bi + 2) / 2 <= t) ++bi;
    while (bi * (bi + 1) / 2 > t) --bi;
    const int bj = t - bi * (bi + 1) / 2;

    const int i0 = bi * 64, j0 = bj * 64;
    const int w0 = s * SW;
    const bool diag = (bi == bj);
    const int tj2 = (threadIdx.x & 15) * 2;
    const int ti2 = (threadIdx.x >> 4) * 2;

    for (int rep = 0; rep < nrep; ++rep) {
        asm volatile("" ::: "memory");

        for (int q = threadIdx.x; q < SW * 32; q += 256) {
            const int wo = q >> 5, cp = (q & 31) * 2;
            const size_t g = (size_t)(w0 + wo) * NBITS;
            *reinterpret_cast<ulonglong2*>(&ldsI[wo][cp]) =
                *reinterpret_cast<const ulonglong2*>(&packed[g + i0 + cp]);
            if (!diag)
                *reinterpret_cast<ulonglong2*>(&ldsJ[wo][cp]) =
                    *reinterpret_cast<const ulonglong2*>(&packed[g + j0 + cp]);
        }
        __syncthreads();

        const u64 (*BJ)[64] = diag ? ldsI : ldsJ;
        int acc[4][4] = {};
#pragma unroll
        for (int w = 0; w < SW; ++w) {
            const u64 a0 = ldsI[w][ti2],      a1 = ldsI[w][ti2 + 1];
            const u64 a2 = ldsI[w][ti2 + 32], a3 = ldsI[w][ti2 + 33];
            const u64 b0 = BJ[w][tj2],        b1 = BJ[w][tj2 + 1];
            const u64 b2 = BJ[w][tj2 + 32],   b3 = BJ[w][tj2 + 33];
            acc[0][0] += __popcll(a0 & b0); acc[0][1] += __popcll(a0 & b1);
            acc[0][2] += __popcll(a0 & b2); acc[0][3] += __popcll(a0 & b3);
            acc[1][0] += __popcll(a1 & b0); acc[1][1] += __popcll(a1 & b1);
            acc[1][2] += __popcll(a1 & b2); acc[1][3] += __popcll(a1 & b3);
            acc[2][0] += __popcll(a2 & b0); acc[2][1] += __popcll(a2 & b1);
            acc[2][2] += __popcll(a2 & b2); acc[2][3] += __popcll(a2 & b3);
            acc[3][0] += __popcll(a3 & b0); acc[3][1] += __popcll(a3 & b1);
            acc[3][2] += __popcll(a3 & b2); acc[3][3] += __popcll(a3 & b3);
        }

        unsigned short* out = Cp + ((size_t)s << 18);
        const int io[4] = {ti2, ti2 + 1, ti2 + 32, ti2 + 33};
#pragma unroll
        for (int a = 0; a < 4; ++a) {
            const size_t row = (size_t)(i0 + io[a]) * NBITS + j0;
            ushort2 u;
            u.x = (unsigned short)acc[a][0]; u.y = (unsigned short)acc[a][1];
            *reinterpret_cast<ushort2*>(&out[row + tj2]) = u;
            u.x = (unsigned short)acc[a][2]; u.y = (unsigned short)acc[a][3];
            *reinterpret_cast<ushort2*>(&out[row + tj2 + 32]) = u;
        }

        if (diag && ti2 == tj2 && rep == 0) {
#pragma unroll
            for (int a = 0; a < 4; ++a)
                atomicAdd(&c1[i0 + io[a]], acc[a][a]);
        }
        __syncthreads();
    }
}

// ---------------------------------------------------------------------------
// Pass 3 (+fused final): MI terms (R9 shape) with DIAGNOSTIC nrep repeat.
// Per rep the full n11-sum + log epilogue recomputes (memory clobber forces
// reloads); keep-alive asm prevents DCE. Reduction + final once.
// t_mi = dispatch_dur / nrep.
// ---------------------------------------------------------------------------
__global__ __launch_bounds__(256) void mi_kernel(const unsigned short* __restrict__ Cp,
                                                 const int* __restrict__ c1,
                                                 const double* __restrict__ lg,
                                                 double* __restrict__ bsum,
                                                 int* __restrict__ bcnt,
                                                 int* __restrict__ done,
                                                 float* __restrict__ out,
                                                 int nrep) {
    const double invB = 1.0 / (double)BATCH;
    const int i = blockIdx.x;
    double lsum = 0.0;
    int lcnt = 0;

    for (int rep = 0; rep < nrep; ++rep) {
        asm volatile("" ::: "memory");
        const int ci = c1[i];
        const double lgB = lg[BATCH];
        lsum = 0.0; lcnt = 0;
#pragma unroll
        for (int half = 0; half < 2; ++half) {
            const int j = half * 256 + threadIdx.x;
            if (j < i) {
                int n11 = 0;
#pragma unroll
                for (int s = 0; s < NSLICE; ++s)
                    n11 += Cp[((size_t)s << 18) + (size_t)i * NBITS + j];
                const int cj = c1[j];

                const int pim[2] = {BATCH - ci, ci};
                const int pjn[2] = {BATCH - cj, cj};
                const int nmn[2][2] = {{BATCH - ci - cj + n11, cj - n11},
                                       {ci - n11, n11}};
#pragma unroll
                for (int m = 0; m < 2; ++m)
#pragma unroll
                    for (int n = 0; n < 2; ++n) {
                        const int c_mn = nmn[m][n];
                        if (c_mn > 0 && pim[m] > 0 && pjn[n] > 0) {
                            lsum += (double)c_mn * invB *
                                    (lg[c_mn] + lgB - lg[pim[m]] - lg[pjn[n]]);
                            ++lcnt;
                        }
                    }
            }
        }
        asm volatile("" : "+v"(lsum), "+v"(lcnt));
    }

    __shared__ double ssum[256];
    __shared__ int scnt[256];
    __shared__ int lastFlag;
    ssum[threadIdx.x] = lsum;
    scnt[threadIdx.x] = lcnt;
    __syncthreads();
    for (int off = 128; off > 0; off >>= 1) {
        if (threadIdx.x < off) {
            ssum[threadIdx.x] += ssum[threadIdx.x + off];
            scnt[threadIdx.x] += scnt[threadIdx.x + off];
        }
        __syncthreads();
    }
    if (threadIdx.x == 0) {
        bsum[i] = ssum[0];
        bcnt[i] = scnt[0];
        __threadfence();
        lastFlag = (atomicAdd(done, 1) == MIGRID - 1);
    }
    __syncthreads();
    if (!lastFlag) return;

    __threadfence();
    double s2 = bsum[threadIdx.x] + bsum[threadIdx.x + 256];
    int c2 = bcnt[threadIdx.x] + bcnt[threadIdx.x + 256];
    __syncthreads();
    ssum[threadIdx.x] = s2;
    scnt[threadIdx.x] = c2;
    __syncthreads();
    for (int off = 128; off > 0; off >>= 1) {
        if (threadIdx.x < off) {
            ssum[threadIdx.x] += ssum[threadIdx.x + off];
            scnt[threadIdx.x] += scnt[threadIdx.x + off];
        }
        __syncthreads();
    }
    if (threadIdx.x == 0) out[0] = (float)(ssum[0] / (double)scnt[0]);
}

// ---------------------------------------------------------------------------
extern "C" void kernel_launch(void* const* d_in, const int* in_sizes, int n_in,
                              void* d_out, int out_size, void* d_ws, size_t ws_size,
                              hipStream_t stream) {
    const float* bits = (const float*)d_in[0];
    char* ws = (char*)d_ws;
    u64*            packed = (u64*)ws;                                   // 2 MB
    unsigned short* Cp     = (unsigned short*)(ws + (2u << 20));         // 16 MB
    double*         lg     = (double*)(ws + (18u << 20));                // 256 KB + 8 B
    int*            c1     = (int*)(ws + (18u << 20) + (512u << 10));    // 2 KB
    int*            done   = (int*)(ws + (18u << 20) + (516u << 10));    // 4 B
    double*         bsum   = (double*)(ws + (18u << 20) + (576u << 10)); // 4 KB
    int*            bcnt   = (int*)(ws + (18u << 20) + (640u << 10));    // 2 KB

    const int GRAM_REP = 8;    // diagnostic repeat knobs
    const int MI_REP   = 16;

    pack_kernel<<<512, 256, 0, stream>>>(bits, packed, lg, c1, done);
    gram_kernel<<<NTILE * NSLICE, 256, 0, stream>>>(packed, Cp, c1, GRAM_REP);
    mi_kernel<<<MIGRID, 256, 0, stream>>>(Cp, c1, lg, bsum, bcnt, done,
                                          (float*)d_out, MI_REP);
}

// Round 11
// 121.194 us; speedup vs baseline: 1.4575x; 1.4575x over previous
//
#include <hip/hip_runtime.h>
#include <stdint.h>

#define BATCH   32768
#define NBITS   512
#define NWORDS  512          // BATCH / 64
#define NSLICE  32           // K-split: 36 tiles * 32 = 1152 blocks
#define SW      16           // words per slice = NWORDS / NSLICE
#define NTILE   36           // 8x8 lower-triangle of 64x64 tiles
#define MIGRID  512

typedef unsigned long long u64;

// ---------------------------------------------------------------------------
// Pass 1 (REDESIGNED + DIAGNOSTIC rep): bit-pack into two u32 planes.
// 2048 wave-tasks: gw -> (word w, row-half h, col-half q). Lane reads float4
// (16 B, coalesced sweet spot), accumulates 4 u32 masks over 32 rows,
// stores ONE coalesced uint4 into plane[h][w*512 + c0]. 2 waves/SIMD TLP.
// Idempotent -> safe to repeat; rep loop for per-kernel counters.
// ---------------------------------------------------------------------------
__global__ __launch_bounds__(256) void pack_kernel(const float* __restrict__ bits,
                                                   unsigned int* __restrict__ plo,
                                                   unsigned int* __restrict__ phi,
                                                   double* __restrict__ lg,
                                                   int* __restrict__ c1,
                                                   int* __restrict__ done,
                                                   int nrep) {
    const int gid = blockIdx.x * 256 + threadIdx.x;   // 0..131071

    if (gid <= BATCH) lg[gid] = (gid > 0) ? log((double)gid) : 0.0;
    if (gid < NBITS) c1[gid] = 0;
    if (gid == NBITS) *done = 0;

    const int wid  = threadIdx.x >> 6;
    const int lane = threadIdx.x & 63;
    const int gw   = blockIdx.x * 4 + wid;    // 0..2047
    const int w    = gw >> 2;                 // word 0..511
    const int h    = (gw >> 1) & 1;           // row half (0: rows 0-31, 1: 32-63)
    const int q    = gw & 1;                  // column half
    const int c0   = q * 256 + lane * 4;

    unsigned int* plane = h ? phi : plo;
    const float* base = bits + ((size_t)w * 64 + h * 32) * NBITS + c0;

    for (int rep = 0; rep < nrep; ++rep) {
        asm volatile("" ::: "memory");
        unsigned int m0 = 0, m1 = 0, m2 = 0, m3 = 0;
#pragma unroll 16
        for (int r = 0; r < 32; ++r) {
            float4 v = *reinterpret_cast<const float4*>(base + (size_t)r * NBITS);
            const unsigned int b = 1u << r;
            if (v.x > 0.0f) m0 |= b;
            if (v.y > 0.0f) m1 |= b;
            if (v.z > 0.0f) m2 |= b;
            if (v.w > 0.0f) m3 |= b;
        }
        uint4 st; st.x = m0; st.y = m1; st.z = m2; st.w = m3;
        *reinterpret_cast<uint4*>(&plane[(size_t)w * NBITS + c0]) = st;
    }
}

// ---------------------------------------------------------------------------
// Pass 2: partial Gram (R9 shape, measured 12.6 us / 75% VALUBusy). Only
// delta: staging reassembles u64 = lo | hi<<32 from the two u32 planes.
// ---------------------------------------------------------------------------
__global__ __launch_bounds__(256) void gram_kernel(const unsigned int* __restrict__ plo,
                                                   const unsigned int* __restrict__ phi,
                                                   unsigned short* __restrict__ Cp,
                                                   int* __restrict__ c1) {
    __shared__ u64 ldsI[SW][64];
    __shared__ u64 ldsJ[SW][64];

    const int s = blockIdx.x & (NSLICE - 1);  // K-slice 0..31
    const int t = blockIdx.x >> 5;            // tile 0..35
    int bi = (int)((sqrtf(8.0f * (float)t + 1.0f) - 1.0f) * 0.5f);
    while ((bi + 1) * (bi + 2) / 2 <= t) ++bi;
    while (bi * (bi + 1) / 2 > t) --bi;
    const int bj = t - bi * (bi + 1) / 2;

    const int i0 = bi * 64, j0 = bj * 64;
    const int w0 = s * SW;
    const bool diag = (bi == bj);

    for (int q = threadIdx.x; q < SW * 32; q += 256) {
        const int wo = q >> 5, cp = (q & 31) * 2;
        const size_t g = (size_t)(w0 + wo) * NBITS;
        {
            uint2 lo = *reinterpret_cast<const uint2*>(&plo[g + i0 + cp]);
            uint2 hi = *reinterpret_cast<const uint2*>(&phi[g + i0 + cp]);
            ulonglong2 st;
            st.x = (u64)lo.x | ((u64)hi.x << 32);
            st.y = (u64)lo.y | ((u64)hi.y << 32);
            *reinterpret_cast<ulonglong2*>(&ldsI[wo][cp]) = st;
        }
        if (!diag) {
            uint2 lo = *reinterpret_cast<const uint2*>(&plo[g + j0 + cp]);
            uint2 hi = *reinterpret_cast<const uint2*>(&phi[g + j0 + cp]);
            ulonglong2 st;
            st.x = (u64)lo.x | ((u64)hi.x << 32);
            st.y = (u64)lo.y | ((u64)hi.y << 32);
            *reinterpret_cast<ulonglong2*>(&ldsJ[wo][cp]) = st;
        }
    }
    __syncthreads();

    const int tj2 = (threadIdx.x & 15) * 2;
    const int ti2 = (threadIdx.x >> 4) * 2;
    const u64 (*BJ)[64] = diag ? ldsI : ldsJ;

    int acc[4][4] = {};
#pragma unroll
    for (int w = 0; w < SW; ++w) {
        const u64 a0 = ldsI[w][ti2],      a1 = ldsI[w][ti2 + 1];
        const u64 a2 = ldsI[w][ti2 + 32], a3 = ldsI[w][ti2 + 33];
        const u64 b0 = BJ[w][tj2],        b1 = BJ[w][tj2 + 1];
        const u64 b2 = BJ[w][tj2 + 32],   b3 = BJ[w][tj2 + 33];
        acc[0][0] += __popcll(a0 & b0); acc[0][1] += __popcll(a0 & b1);
        acc[0][2] += __popcll(a0 & b2); acc[0][3] += __popcll(a0 & b3);
        acc[1][0] += __popcll(a1 & b0); acc[1][1] += __popcll(a1 & b1);
        acc[1][2] += __popcll(a1 & b2); acc[1][3] += __popcll(a1 & b3);
        acc[2][0] += __popcll(a2 & b0); acc[2][1] += __popcll(a2 & b1);
        acc[2][2] += __popcll(a2 & b2); acc[2][3] += __popcll(a2 & b3);
        acc[3][0] += __popcll(a3 & b0); acc[3][1] += __popcll(a3 & b1);
        acc[3][2] += __popcll(a3 & b2); acc[3][3] += __popcll(a3 & b3);
    }

    unsigned short* out = Cp + ((size_t)s << 18);
    const int io[4] = {ti2, ti2 + 1, ti2 + 32, ti2 + 33};
#pragma unroll
    for (int a = 0; a < 4; ++a) {
        const size_t row = (size_t)(i0 + io[a]) * NBITS + j0;
        ushort2 u;
        u.x = (unsigned short)acc[a][0]; u.y = (unsigned short)acc[a][1];
        *reinterpret_cast<ushort2*>(&out[row + tj2]) = u;
        u.x = (unsigned short)acc[a][2]; u.y = (unsigned short)acc[a][3];
        *reinterpret_cast<ushort2*>(&out[row + tj2 + 32]) = u;
    }

    if (diag && ti2 == tj2) {
#pragma unroll
        for (int a = 0; a < 4; ++a)
            atomicAdd(&c1[i0 + io[a]], acc[a][a]);
    }
}

// ---------------------------------------------------------------------------
// Pass 3 (+fused final): unchanged from R9 (measured ~2.4 us).
// ---------------------------------------------------------------------------
__global__ __launch_bounds__(256) void mi_kernel(const unsigned short* __restrict__ Cp,
                                                 const int* __restrict__ c1,
                                                 const double* __restrict__ lg,
                                                 double* __restrict__ bsum,
                                                 int* __restrict__ bcnt,
                                                 int* __restrict__ done,
                                                 float* __restrict__ out) {
    const double invB = 1.0 / (double)BATCH;
    const int i = blockIdx.x;
    const int ci = c1[i];
    const double lgB = lg[BATCH];
    double lsum = 0.0;
    int lcnt = 0;

#pragma unroll
    for (int half = 0; half < 2; ++half) {
        const int j = half * 256 + threadIdx.x;
        if (j < i) {
            int n11 = 0;
#pragma unroll
            for (int s = 0; s < NSLICE; ++s)
                n11 += Cp[((size_t)s << 18) + (size_t)i * NBITS + j];
            const int cj = c1[j];

            const int pim[2] = {BATCH - ci, ci};
            const int pjn[2] = {BATCH - cj, cj};
            const int nmn[2][2] = {{BATCH - ci - cj + n11, cj - n11},
                                   {ci - n11, n11}};
#pragma unroll
            for (int m = 0; m < 2; ++m)
#pragma unroll
                for (int n = 0; n < 2; ++n) {
                    const int c_mn = nmn[m][n];
                    if (c_mn > 0 && pim[m] > 0 && pjn[n] > 0) {
                        lsum += (double)c_mn * invB *
                                (lg[c_mn] + lgB - lg[pim[m]] - lg[pjn[n]]);
                        ++lcnt;
                    }
                }
        }
    }

    __shared__ double ssum[256];
    __shared__ int scnt[256];
    __shared__ int lastFlag;
    ssum[threadIdx.x] = lsum;
    scnt[threadIdx.x] = lcnt;
    __syncthreads();
    for (int off = 128; off > 0; off >>= 1) {
        if (threadIdx.x < off) {
            ssum[threadIdx.x] += ssum[threadIdx.x + off];
            scnt[threadIdx.x] += scnt[threadIdx.x + off];
        }
        __syncthreads();
    }
    if (threadIdx.x == 0) {
        bsum[i] = ssum[0];
        bcnt[i] = scnt[0];
        __threadfence();
        lastFlag = (atomicAdd(done, 1) == MIGRID - 1);
    }
    __syncthreads();
    if (!lastFlag) return;

    __threadfence();
    double s2 = bsum[threadIdx.x] + bsum[threadIdx.x + 256];
    int c2 = bcnt[threadIdx.x] + bcnt[threadIdx.x + 256];
    __syncthreads();
    ssum[threadIdx.x] = s2;
    scnt[threadIdx.x] = c2;
    __syncthreads();
    for (int off = 128; off > 0; off >>= 1) {
        if (threadIdx.x < off) {
            ssum[threadIdx.x] += ssum[threadIdx.x + off];
            scnt[threadIdx.x] += scnt[threadIdx.x + off];
        }
        __syncthreads();
    }
    if (threadIdx.x == 0) out[0] = (float)(ssum[0] / (double)scnt[0]);
}

// ---------------------------------------------------------------------------
extern "C" void kernel_launch(void* const* d_in, const int* in_sizes, int n_in,
                              void* d_out, int out_size, void* d_ws, size_t ws_size,
                              hipStream_t stream) {
    const float* bits = (const float*)d_in[0];
    char* ws = (char*)d_ws;
    unsigned int*   plo  = (unsigned int*)ws;                            // 1 MB
    unsigned int*   phi  = (unsigned int*)(ws + (1u << 20));             // 1 MB
    unsigned short* Cp   = (unsigned short*)(ws + (2u << 20));           // 16 MB
    double*         lg   = (double*)(ws + (18u << 20));                  // 256 KB + 8 B
    int*            c1   = (int*)(ws + (18u << 20) + (512u << 10));      // 2 KB
    int*            done = (int*)(ws + (18u << 20) + (516u << 10));      // 4 B
    double*         bsum = (double*)(ws + (18u << 20) + (576u << 10));   // 4 KB
    int*            bcnt = (int*)(ws + (18u << 20) + (640u << 10));      // 2 KB

    const int PACK_REP = 8;   // diagnostic repeat

    pack_kernel<<<512, 256, 0, stream>>>(bits, plo, phi, lg, c1, done, PACK_REP);
    gram_kernel<<<NTILE * NSLICE, 256, 0, stream>>>(plo, phi, Cp, c1);
    mi_kernel<<<MIGRID, 256, 0, stream>>>(Cp, c1, lg, bsum, bcnt, done, (float*)d_out);
}

// Round 12
// 52.141 us; speedup vs baseline: 3.3878x; 2.3244x over previous
//
#include <hip/hip_runtime.h>
#include <stdint.h>

#define BATCH   32768
#define NBITS   512
#define NWORDS  512          // BATCH / 64
#define NSLICE  32           // K-split: 36 tiles * 32 = 1152 blocks
#define SW      16           // words per slice = NWORDS / NSLICE
#define NTILE   36           // 8x8 lower-triangle of 64x64 tiles
#define MIGRID  512

typedef unsigned long long u64;

// ---------------------------------------------------------------------------
// Pass 1: bit-pack into two u32 planes (measured ~11 us, at BW roofline).
// 2048 wave-tasks: gw -> (word w, row-half h, col-half q). Lane reads float4
// (16 B coalescing sweet spot), accumulates 4 u32 masks over 32 rows,
// stores one coalesced uint4 into plane[h]. Also builds the f64 log table
// and zeroes c1/done.
// ---------------------------------------------------------------------------
__global__ __launch_bounds__(256) void pack_kernel(const float* __restrict__ bits,
                                                   unsigned int* __restrict__ plo,
                                                   unsigned int* __restrict__ phi,
                                                   double* __restrict__ lg,
                                                   int* __restrict__ c1,
                                                   int* __restrict__ done) {
    const int gid = blockIdx.x * 256 + threadIdx.x;   // 0..131071

    if (gid <= BATCH) lg[gid] = (gid > 0) ? log((double)gid) : 0.0;
    if (gid < NBITS) c1[gid] = 0;
    if (gid == NBITS) *done = 0;

    const int wid  = threadIdx.x >> 6;
    const int lane = threadIdx.x & 63;
    const int gw   = blockIdx.x * 4 + wid;    // 0..2047
    const int w    = gw >> 2;                 // word 0..511
    const int h    = (gw >> 1) & 1;           // row half (0: rows 0-31, 1: 32-63)
    const int q    = gw & 1;                  // column half
    const int c0   = q * 256 + lane * 4;

    unsigned int* plane = h ? phi : plo;
    const float* base = bits + ((size_t)w * 64 + h * 32) * NBITS + c0;

    unsigned int m0 = 0, m1 = 0, m2 = 0, m3 = 0;
#pragma unroll 16
    for (int r = 0; r < 32; ++r) {
        float4 v = *reinterpret_cast<const float4*>(base + (size_t)r * NBITS);
        const unsigned int b = 1u << r;
        if (v.x > 0.0f) m0 |= b;
        if (v.y > 0.0f) m1 |= b;
        if (v.z > 0.0f) m2 |= b;
        if (v.w > 0.0f) m3 |= b;
    }
    uint4 st; st.x = m0; st.y = m1; st.z = m2; st.w = m3;
    *reinterpret_cast<uint4*>(&plane[(size_t)w * NBITS + c0]) = st;
}

// ---------------------------------------------------------------------------
// Pass 2: partial Gram (measured ~12.6 us, 75% VALUBusy, 0 bank conflicts).
// Block = (tile t of 36 [64x64], slice s of 32 [16 words]), 256 threads,
// 4x4 register tile, interleaved cols {x,x+1,x+32,x+33}. Staging
// reassembles u64 = lo | hi<<32 from the two u32 planes.
// ---------------------------------------------------------------------------
__global__ __launch_bounds__(256) void gram_kernel(const unsigned int* __restrict__ plo,
                                                   const unsigned int* __restrict__ phi,
                                                   unsigned short* __restrict__ Cp,
                                                   int* __restrict__ c1) {
    __shared__ u64 ldsI[SW][64];
    __shared__ u64 ldsJ[SW][64];

    const int s = blockIdx.x & (NSLICE - 1);  // K-slice 0..31
    const int t = blockIdx.x >> 5;            // tile 0..35
    int bi = (int)((sqrtf(8.0f * (float)t + 1.0f) - 1.0f) * 0.5f);
    while ((bi + 1) * (bi + 2) / 2 <= t) ++bi;
    while (bi * (bi + 1) / 2 > t) --bi;
    const int bj = t - bi * (bi + 1) / 2;

    const int i0 = bi * 64, j0 = bj * 64;
    const int w0 = s * SW;
    const bool diag = (bi == bj);

    for (int q = threadIdx.x; q < SW * 32; q += 256) {
        const int wo = q >> 5, cp = (q & 31) * 2;
        const size_t g = (size_t)(w0 + wo) * NBITS;
        {
            uint2 lo = *reinterpret_cast<const uint2*>(&plo[g + i0 + cp]);
            uint2 hi = *reinterpret_cast<const uint2*>(&phi[g + i0 + cp]);
            ulonglong2 st;
            st.x = (u64)lo.x | ((u64)hi.x << 32);
            st.y = (u64)lo.y | ((u64)hi.y << 32);
            *reinterpret_cast<ulonglong2*>(&ldsI[wo][cp]) = st;
        }
        if (!diag) {
            uint2 lo = *reinterpret_cast<const uint2*>(&plo[g + j0 + cp]);
            uint2 hi = *reinterpret_cast<const uint2*>(&phi[g + j0 + cp]);
            ulonglong2 st;
            st.x = (u64)lo.x | ((u64)hi.x << 32);
            st.y = (u64)lo.y | ((u64)hi.y << 32);
            *reinterpret_cast<ulonglong2*>(&ldsJ[wo][cp]) = st;
        }
    }
    __syncthreads();

    const int tj2 = (threadIdx.x & 15) * 2;
    const int ti2 = (threadIdx.x >> 4) * 2;
    const u64 (*BJ)[64] = diag ? ldsI : ldsJ;

    int acc[4][4] = {};
#pragma unroll
    for (int w = 0; w < SW; ++w) {
        const u64 a0 = ldsI[w][ti2],      a1 = ldsI[w][ti2 + 1];
        const u64 a2 = ldsI[w][ti2 + 32], a3 = ldsI[w][ti2 + 33];
        const u64 b0 = BJ[w][tj2],        b1 = BJ[w][tj2 + 1];
        const u64 b2 = BJ[w][tj2 + 32],   b3 = BJ[w][tj2 + 33];
        acc[0][0] += __popcll(a0 & b0); acc[0][1] += __popcll(a0 & b1);
        acc[0][2] += __popcll(a0 & b2); acc[0][3] += __popcll(a0 & b3);
        acc[1][0] += __popcll(a1 & b0); acc[1][1] += __popcll(a1 & b1);
        acc[1][2] += __popcll(a1 & b2); acc[1][3] += __popcll(a1 & b3);
        acc[2][0] += __popcll(a2 & b0); acc[2][1] += __popcll(a2 & b1);
        acc[2][2] += __popcll(a2 & b2); acc[2][3] += __popcll(a2 & b3);
        acc[3][0] += __popcll(a3 & b0); acc[3][1] += __popcll(a3 & b1);
        acc[3][2] += __popcll(a3 & b2); acc[3][3] += __popcll(a3 & b3);
    }

    unsigned short* out = Cp + ((size_t)s << 18);
    const int io[4] = {ti2, ti2 + 1, ti2 + 32, ti2 + 33};
#pragma unroll
    for (int a = 0; a < 4; ++a) {
        const size_t row = (size_t)(i0 + io[a]) * NBITS + j0;
        ushort2 u;
        u.x = (unsigned short)acc[a][0]; u.y = (unsigned short)acc[a][1];
        *reinterpret_cast<ushort2*>(&out[row + tj2]) = u;
        u.x = (unsigned short)acc[a][2]; u.y = (unsigned short)acc[a][3];
        *reinterpret_cast<ushort2*>(&out[row + tj2 + 32]) = u;
    }

    if (diag && ti2 == tj2) {
#pragma unroll
        for (int a = 0; a < 4; ++a)
            atomicAdd(&c1[i0 + io[a]], acc[a][a]);
    }
}

// ---------------------------------------------------------------------------
// Pass 3 (+fused final): per-pair MI terms (measured ~2.4 us).
// ---------------------------------------------------------------------------
__global__ __launch_bounds__(256) void mi_kernel(const unsigned short* __restrict__ Cp,
                                                 const int* __restrict__ c1,
                                                 const double* __restrict__ lg,
                                                 double* __restrict__ bsum,
                                                 int* __restrict__ bcnt,
                                                 int* __restrict__ done,
                                                 float* __restrict__ out) {
    const double invB = 1.0 / (double)BATCH;
    const int i = blockIdx.x;
    const int ci = c1[i];
    const double lgB = lg[BATCH];
    double lsum = 0.0;
    int lcnt = 0;

#pragma unroll
    for (int half = 0; half < 2; ++half) {
        const int j = half * 256 + threadIdx.x;
        if (j < i) {
            int n11 = 0;
#pragma unroll
            for (int s = 0; s < NSLICE; ++s)
                n11 += Cp[((size_t)s << 18) + (size_t)i * NBITS + j];
            const int cj = c1[j];

            const int pim[2] = {BATCH - ci, ci};
            const int pjn[2] = {BATCH - cj, cj};
            const int nmn[2][2] = {{BATCH - ci - cj + n11, cj - n11},
                                   {ci - n11, n11}};
#pragma unroll
            for (int m = 0; m < 2; ++m)
#pragma unroll
                for (int n = 0; n < 2; ++n) {
                    const int c_mn = nmn[m][n];
                    if (c_mn > 0 && pim[m] > 0 && pjn[n] > 0) {
                        lsum += (double)c_mn * invB *
                                (lg[c_mn] + lgB - lg[pim[m]] - lg[pjn[n]]);
                        ++lcnt;
                    }
                }
        }
    }

    __shared__ double ssum[256];
    __shared__ int scnt[256];
    __shared__ int lastFlag;
    ssum[threadIdx.x] = lsum;
    scnt[threadIdx.x] = lcnt;
    __syncthreads();
    for (int off = 128; off > 0; off >>= 1) {
        if (threadIdx.x < off) {
            ssum[threadIdx.x] += ssum[threadIdx.x + off];
            scnt[threadIdx.x] += scnt[threadIdx.x + off];
        }
        __syncthreads();
    }
    if (threadIdx.x == 0) {
        bsum[i] = ssum[0];
        bcnt[i] = scnt[0];
        __threadfence();
        lastFlag = (atomicAdd(done, 1) == MIGRID - 1);
    }
    __syncthreads();
    if (!lastFlag) return;

    __threadfence();
    double s2 = bsum[threadIdx.x] + bsum[threadIdx.x + 256];
    int c2 = bcnt[threadIdx.x] + bcnt[threadIdx.x + 256];
    __syncthreads();
    ssum[threadIdx.x] = s2;
    scnt[threadIdx.x] = c2;
    __syncthreads();
    for (int off = 128; off > 0; off >>= 1) {
        if (threadIdx.x < off) {
            ssum[threadIdx.x] += ssum[threadIdx.x + off];
            scnt[threadIdx.x] += scnt[threadIdx.x + off];
        }
        __syncthreads();
    }
    if (threadIdx.x == 0) out[0] = (float)(ssum[0] / (double)scnt[0]);
}

// ---------------------------------------------------------------------------
extern "C" void kernel_launch(void* const* d_in, const int* in_sizes, int n_in,
                              void* d_out, int out_size, void* d_ws, size_t ws_size,
                              hipStream_t stream) {
    const float* bits = (const float*)d_in[0];
    char* ws = (char*)d_ws;
    unsigned int*   plo  = (unsigned int*)ws;                            // 1 MB
    unsigned int*   phi  = (unsigned int*)(ws + (1u << 20));             // 1 MB
    unsigned short* Cp   = (unsigned short*)(ws + (2u << 20));           // 16 MB
    double*         lg   = (double*)(ws + (18u << 20));                  // 256 KB + 8 B
    int*            c1   = (int*)(ws + (18u << 20) + (512u << 10));      // 2 KB
    int*            done = (int*)(ws + (18u << 20) + (516u << 10));      // 4 B
    double*         bsum = (double*)(ws + (18u << 20) + (576u << 10));   // 4 KB
    int*            bcnt = (int*)(ws + (18u << 20) + (640u << 10));      // 2 KB

    pack_kernel<<<512, 256, 0, stream>>>(bits, plo, phi, lg, c1, done);
    gram_kernel<<<NTILE * NSLICE, 256, 0, stream>>>(plo, phi, Cp, c1);
    mi_kernel<<<MIGRID, 256, 0, stream>>>(Cp, c1, lg, bsum, bcnt, done, (float*)d_out);
}